// Round 10
// baseline (554.836 us; speedup 1.0000x reference)
//
#include <hip/hip_runtime.h>
#include <hip/hip_bf16.h>
#include <math.h>

#define SS 2048
#define EE 768
#define HH 12
#define DHH 64
#define FFF 3072
#define LL 4

typedef __hip_bfloat16 bf16;
typedef __attribute__((ext_vector_type(8))) short short8;
typedef __attribute__((ext_vector_type(4))) float f32x4;

__device__ __forceinline__ float b2f(short u) {
  union { unsigned int i; float f; } v;
  v.i = ((unsigned int)(unsigned short)u) << 16;
  return v.f;
}
__device__ __forceinline__ bf16 f2b(float f) { return __float2bfloat16(f); }
__device__ __forceinline__ unsigned int f2bu(float f) {
  return (unsigned int)__bfloat16_as_ushort(__float2bfloat16(f));
}

__device__ __forceinline__ void async_ld16(const void* g, void* l) {
  __builtin_amdgcn_global_load_lds(
      (const __attribute__((address_space(1))) void*)g,
      (__attribute__((address_space(3))) void*)l, 16, 0, 0);
}

// ---------------------------------------------------------------------------
// Fused LN: v = (readx ? x : 0) + bias + sum(parts) + extra; optional x
// writeback; out = LN(v).
// ---------------------------------------------------------------------------
template <typename OutT>
__global__ __launch_bounds__(256) void ln_fused_kernel(
    float* x, const float* __restrict__ bias, const float* __restrict__ part,
    int nparts, const float* __restrict__ extra,
    const float* __restrict__ g, const float* __restrict__ bta,
    int writeback, int readx, OutT* __restrict__ out) {
  int row = blockIdx.x;
  int tid = threadIdx.x;
  float* xr = x + (size_t)row * EE;
  float v0 = 0.f, v1 = 0.f, v2 = 0.f;
  if (readx) { v0 = xr[tid]; v1 = xr[tid + 256]; v2 = xr[tid + 512]; }
  if (bias) { v0 += bias[tid]; v1 += bias[tid + 256]; v2 += bias[tid + 512]; }
  for (int p = 0; p < nparts; p++) {
    const float* pr = part + (size_t)p * SS * EE + (size_t)row * EE;
    v0 += pr[tid]; v1 += pr[tid + 256]; v2 += pr[tid + 512];
  }
  if (extra) {
    const float* er = extra + (size_t)row * EE;
    v0 += er[tid]; v1 += er[tid + 256]; v2 += er[tid + 512];
  }
  if (writeback) { xr[tid] = v0; xr[tid + 256] = v1; xr[tid + 512] = v2; }
  float s  = v0 + v1 + v2;
  float s2 = v0 * v0 + v1 * v1 + v2 * v2;
  #pragma unroll
  for (int off = 32; off >= 1; off >>= 1) {
    s  += __shfl_down(s,  off);
    s2 += __shfl_down(s2, off);
  }
  __shared__ float red[8];
  __shared__ float mb[2];
  int lane = tid & 63, wid = tid >> 6;
  if (lane == 0) { red[wid] = s; red[4 + wid] = s2; }
  __syncthreads();
  if (tid == 0) {
    float ts  = red[0] + red[1] + red[2] + red[3];
    float ts2 = red[4] + red[5] + red[6] + red[7];
    float mu  = ts * (1.0f / EE);
    float var = ts2 * (1.0f / EE) - mu * mu;
    mb[0] = mu; mb[1] = rsqrtf(var + 1e-5f);
  }
  __syncthreads();
  float mu = mb[0], rs = mb[1];
  OutT* orow = out + (size_t)row * EE;
  float o0 = (v0 - mu) * rs * g[tid]       + bta[tid];
  float o1 = (v1 - mu) * rs * g[tid + 256] + bta[tid + 256];
  float o2 = (v2 - mu) * rs * g[tid + 512] + bta[tid + 512];
  if constexpr (sizeof(OutT) == 4) {
    orow[tid] = o0; orow[tid + 256] = o1; orow[tid + 512] = o2;
  } else {
    orow[tid] = f2b(o0); orow[tid + 256] = f2b(o1); orow[tid + 512] = f2b(o2);
  }
}

// ---------------------------------------------------------------------------
// Mega-transpose: known-good 64k x 32n [32][33] version (0 bank conflicts,
// accepted floor). Block 13824 does the qkv bias concat.
// ---------------------------------------------------------------------------
__global__ __launch_bounds__(256) void transpose_all_kernel(
    const float* __restrict__ Wq, const float* __restrict__ Wk,
    const float* __restrict__ Wv, const float* __restrict__ Wo,
    const float* __restrict__ W1, const float* __restrict__ W2,
    bf16* __restrict__ WtAll,
    const float* __restrict__ bq, const float* __restrict__ bk,
    const float* __restrict__ bv, float* __restrict__ bqkvA) {
  int bid = blockIdx.x;
  if (bid == 13824) {  // bias concat: 4 layers x 2304
    #pragma unroll
    for (int i = 0; i < 36; i++) {
      int gidx = i * 256 + threadIdx.x;
      int l = gidx / 2304, ii = gidx % 2304;
      bqkvA[gidx] = (ii < 768) ? bq[l * 768 + ii]
                  : (ii < 1536 ? bk[l * 768 + ii - 768] : bv[l * 768 + ii - 1536]);
    }
    return;
  }
  __shared__ unsigned int lds[32][33];
  int l = bid / 3456, r = bid % 3456;
  bf16* base = WtAll + (size_t)l * 7077888;
  const float* src; bf16* dst; int K, N, rr;
  if (r < 864) {
    int m = r / 288; rr = r % 288;
    src = (m == 0 ? Wq : m == 1 ? Wk : Wv) + (size_t)l * EE * EE;
    dst = base + (size_t)m * 589824; K = 768; N = 768;
  } else if (r < 1152) {
    rr = r - 864; src = Wo + (size_t)l * EE * EE; dst = base + 1769472; K = 768; N = 768;
  } else if (r < 2304) {
    rr = r - 1152; src = W1 + (size_t)l * EE * FFF; dst = base + 2359296; K = 768; N = 3072;
  } else {
    rr = r - 2304; src = W2 + (size_t)l * FFF * EE; dst = base + 4718592; K = 3072; N = 768;
  }
  int ntn = N >> 5;
  int k0 = (rr / ntn) * 64, n0 = (rr % ntn) * 32;
  int kp = threadIdx.x >> 3, ns = (threadIdx.x & 7) * 4;
  const float* s0 = src + (size_t)(k0 + 2 * kp) * N + n0 + ns;
  float4 e = *(const float4*)s0;
  float4 o = *(const float4*)(s0 + N);
  lds[ns + 0][kp] = (f2bu(o.x) << 16) | f2bu(e.x);
  lds[ns + 1][kp] = (f2bu(o.y) << 16) | f2bu(e.y);
  lds[ns + 2][kp] = (f2bu(o.z) << 16) | f2bu(e.z);
  lds[ns + 3][kp] = (f2bu(o.w) << 16) | f2bu(e.w);
  __syncthreads();
  int n = threadIdx.x >> 3, kp4 = (threadIdx.x & 7) * 4;
  uint4 ov;
  ov.x = lds[n][kp4];     ov.y = lds[n][kp4 + 1];
  ov.z = lds[n][kp4 + 2]; ov.w = lds[n][kp4 + 3];
  unsigned int* d = (unsigned int*)dst + (size_t)(n0 + n) * (K >> 1) + (k0 >> 1) + kp4;
  *(uint4*)d = ov;
}

// ---------------------------------------------------------------------------
// bf16 MFMA GEMM, 64 x (NF*32) tile, 2-phase double-buffered, __syncthreads
// drain (round-7 known-good loop — counted-vmcnt variant failed the
// container twice, suspected hang; reverted). NF=4: 64x128 (FF1 grid 768 =
// 3.0/CU). NF=3: 64x96 (QKV 768 = 3.0/CU; FF2 512 = 2.0/CU). 4 waves (2x2),
// BK=64, XOR swizzle, 16B global_load_lds.
// Modes: 1: GELU->bf16 (ld N)
//        4: QKV: n<768 -> Cv bf16 ld 768; n>=768 -> transposed short4 into
//           Cv2 = kvT[(n-768)][2048]
//        2: split-K fp32 partial: part[z*S*E + idx] = acc (no bias)
// ---------------------------------------------------------------------------
template <int NF>
__global__ __launch_bounds__(256) void gemm_mn_kernel(
    const bf16* __restrict__ A, int lda, const bf16* __restrict__ Bt,
    const float* __restrict__ bias, void* __restrict__ Cv, void* __restrict__ Cv2,
    float* __restrict__ part, int K, int N, int mode, int Ksplit) {
  __shared__ __align__(16) short As[2][64 * 64];        // 2 x 8 KB
  __shared__ __align__(16) short Bs[2][NF * 32 * 64];   // 2 x NF*4 KB
  const int t = threadIdx.x;
  const int wave = t >> 6, lane = t & 63;
  const int m0 = blockIdx.y * 64, n0 = blockIdx.x * (NF * 32);

  const int srow = t >> 3;                  // 0..31
  const int sw   = (t & 7) ^ (srow & 7);    // XOR-swizzled 8-elem chunk
  const bf16* Ag = A  + (size_t)(m0 + srow) * lda + sw * 8;
  const bf16* Bg = Bt + (size_t)(n0 + srow) * K + sw * 8;

  const int fr = lane & 15, kq = lane >> 4;
  const int wm = (wave >> 1) * 32, wn = (wave & 1) * (NF * 16);
  f32x4 acc[2][NF] = {};

  int kBeg = 0, kEnd = K;
  if (mode == 2) { kBeg = blockIdx.z * Ksplit; kEnd = kBeg + Ksplit; }
  const int nIt = (kEnd - kBeg) >> 6;

  {
    const int k0 = kBeg;
    #pragma unroll
    for (int q = 0; q < 2; q++)
      async_ld16(Ag + (size_t)(q * 32) * lda + k0, As[0] + q * 2048 + wave * 512);
    #pragma unroll
    for (int q = 0; q < NF; q++)
      async_ld16(Bg + (size_t)(q * 32) * K + k0, Bs[0] + q * 2048 + wave * 512);
  }
  __syncthreads();

  for (int it = 0; it < nIt; ++it) {
    const int cur = it & 1;
    if (it + 1 < nIt) {
      const int k0 = kBeg + (it + 1) * 64;
      short* Ad = As[cur ^ 1];
      short* Bd = Bs[cur ^ 1];
      #pragma unroll
      for (int q = 0; q < 2; q++)
        async_ld16(Ag + (size_t)(q * 32) * lda + k0, Ad + q * 2048 + wave * 512);
      #pragma unroll
      for (int q = 0; q < NF; q++)
        async_ld16(Bg + (size_t)(q * 32) * K + k0, Bd + q * 2048 + wave * 512);
    }
    const short* Ac = As[cur];
    const short* Bc = Bs[cur];
    #pragma unroll
    for (int s = 0; s < 2; s++) {
      short8 a[2], b[NF];
      #pragma unroll
      for (int i = 0; i < 2; i++) {
        int r = wm + 16 * i + fr;
        int p = (kq + 4 * s) ^ (r & 7);
        a[i] = *(const short8*)(Ac + r * 64 + p * 8);
      }
      #pragma unroll
      for (int j = 0; j < NF; j++) {
        int r = wn + 16 * j + fr;
        int p = (kq + 4 * s) ^ (r & 7);
        b[j] = *(const short8*)(Bc + r * 64 + p * 8);
      }
      #pragma unroll
      for (int i = 0; i < 2; i++)
        #pragma unroll
        for (int j = 0; j < NF; j++)
          acc[i][j] = __builtin_amdgcn_mfma_f32_16x16x32_bf16(a[i], b[j], acc[i][j], 0, 0, 0);
    }
    __syncthreads();
  }

  // C/D layout: col = lane&15, row = (lane>>4)*4 + reg
  #pragma unroll
  for (int i = 0; i < 2; i++) {
    #pragma unroll
    for (int j = 0; j < NF; j++) {
      const int r0 = m0 + wm + 16 * i + kq * 4;
      const int c  = n0 + wn + 16 * j + fr;
      if (mode == 2) {
        #pragma unroll
        for (int ri = 0; ri < 4; ri++)
          part[(size_t)blockIdx.z * SS * EE + (size_t)(r0 + ri) * EE + c] =
              acc[i][j][ri];
      } else if (mode == 4) {
        const float bv = bias[c];
        if (n0 < 768) {
          #pragma unroll
          for (int ri = 0; ri < 4; ri++)
            ((bf16*)Cv)[(size_t)(r0 + ri) * 768 + c] = f2b(acc[i][j][ri] + bv);
        } else {
          __align__(8) bf16 tb[4];
          #pragma unroll
          for (int ri = 0; ri < 4; ri++) tb[ri] = f2b(acc[i][j][ri] + bv);
          *(short4*)((short*)Cv2 + ((size_t)(c - 768) << 11) + r0) = *(short4*)&tb[0];
        }
      } else {
        const float bv = bias[c];
        #pragma unroll
        for (int ri = 0; ri < 4; ri++) {
          float val = acc[i][j][ri] + bv;
          val = 0.5f * val * (1.0f + erff(val * 0.70710678118654752f));
          ((bf16*)Cv)[(size_t)(r0 + ri) * N + c] = f2b(val);
        }
      }
    }
  }
}

// ---------------------------------------------------------------------------
// Residual GEMM (fp32 out), 64x64 tile, N = 768, 2-phase double-buffered
// (known-good). x[idx] = acc + bias + x[idx]. grid (12, 32). 32 KB.
// ---------------------------------------------------------------------------
__global__ __launch_bounds__(256) void gemm_resid_kernel(
    const bf16* __restrict__ A, int lda, const bf16* __restrict__ Bt,
    const float* __restrict__ bias, float* __restrict__ x, int K) {
  __shared__ __align__(16) short As[2][64 * 64];
  __shared__ __align__(16) short Bs[2][64 * 64];
  const int t = threadIdx.x;
  const int wave = t >> 6, lane = t & 63;
  const int m0 = blockIdx.y * 64, n0 = blockIdx.x * 64;

  const int srow = t >> 3;
  const int sw   = (t & 7) ^ (srow & 7);
  const bf16* Ag = A  + (size_t)(m0 + srow) * lda + sw * 8;
  const bf16* Bg = Bt + (size_t)(n0 + srow) * K + sw * 8;

  const int fr = lane & 15, kq = lane >> 4;
  const int wm = (wave >> 1) * 32, wn = (wave & 1) * 32;
  f32x4 acc[2][2] = {};
  const int nIt = K >> 6;

  {
    async_ld16(Ag,                    As[0] + wave * 512);
    async_ld16(Ag + (size_t)32 * lda, As[0] + 2048 + wave * 512);
    async_ld16(Bg,                    Bs[0] + wave * 512);
    async_ld16(Bg + (size_t)32 * K,   Bs[0] + 2048 + wave * 512);
  }
  __syncthreads();

  for (int it = 0; it < nIt; ++it) {
    const int cur = it & 1;
    if (it + 1 < nIt) {
      const int k0 = (it + 1) * 64;
      short* Ad = As[cur ^ 1];
      short* Bd = Bs[cur ^ 1];
      async_ld16(Ag + k0,                    Ad + wave * 512);
      async_ld16(Ag + (size_t)32 * lda + k0, Ad + 2048 + wave * 512);
      async_ld16(Bg + k0,                    Bd + wave * 512);
      async_ld16(Bg + (size_t)32 * K + k0,   Bd + 2048 + wave * 512);
    }
    const short* Ac = As[cur];
    const short* Bc = Bs[cur];
    #pragma unroll
    for (int s = 0; s < 2; s++) {
      short8 a[2], b[2];
      #pragma unroll
      for (int i = 0; i < 2; i++) {
        int r = wm + 16 * i + fr;
        int p = (kq + 4 * s) ^ (r & 7);
        a[i] = *(const short8*)(Ac + r * 64 + p * 8);
      }
      #pragma unroll
      for (int j = 0; j < 2; j++) {
        int r = wn + 16 * j + fr;
        int p = (kq + 4 * s) ^ (r & 7);
        b[j] = *(const short8*)(Bc + r * 64 + p * 8);
      }
      #pragma unroll
      for (int i = 0; i < 2; i++)
        #pragma unroll
        for (int j = 0; j < 2; j++)
          acc[i][j] = __builtin_amdgcn_mfma_f32_16x16x32_bf16(a[i], b[j], acc[i][j], 0, 0, 0);
    }
    __syncthreads();
  }

  #pragma unroll
  for (int i = 0; i < 2; i++) {
    #pragma unroll
    for (int j = 0; j < 2; j++) {
      const int r0 = m0 + wm + 16 * i + kq * 4;
      const int c  = n0 + wn + 16 * j + fr;
      const float bv = bias[c];
      #pragma unroll
      for (int ri = 0; ri < 4; ri++) {
        const size_t idx = (size_t)(r0 + ri) * EE + c;
        x[idx] = acc[i][j][ri] + bv + x[idx];
      }
    }
  }
}

// ---------------------------------------------------------------------------
// Attention phase 1 (dedup): partial M_h = K_h^T V_h over an s-chunk of 256.
// grid (12 heads, 8 chunks) = 96 blocks (2x the round-7 parallelism).
// Writes fp32 partials.
// ---------------------------------------------------------------------------
__global__ __launch_bounds__(256) void attn_kv_kernel(
    const bf16* __restrict__ kvT, float* __restrict__ Mpart) {
  __shared__ short pbuf[4][4096];
  const int h = blockIdx.x, c = blockIdx.y;
  const int lane = threadIdx.x & 63, wave = threadIdx.x >> 6;
  const int fr = lane & 15, kq = lane >> 4;
  const short* kT = (const short*)kvT + (size_t)h * 64 * 2048;
  const short* vT = (const short*)kvT + (size_t)(768 + h * 64) * 2048;

  f32x4 acc[4][4] = {};
  {
    const int s0 = c * 256 + wave * 64;
    #pragma unroll
    for (int s = 0; s < 2; s++) {
      short8 a[4], b[4];
      #pragma unroll
      for (int i = 0; i < 4; i++)
        a[i] = *(const short8*)(kT + (size_t)(16 * i + fr) * 2048 + s0 + s * 32 + kq * 8);
      #pragma unroll
      for (int j = 0; j < 4; j++)
        b[j] = *(const short8*)(vT + (size_t)(16 * j + fr) * 2048 + s0 + s * 32 + kq * 8);
      #pragma unroll
      for (int i = 0; i < 4; i++)
        #pragma unroll
        for (int j = 0; j < 4; j++)
          acc[i][j] = __builtin_amdgcn_mfma_f32_16x16x32_bf16(a[i], b[j], acc[i][j], 0, 0, 0);
    }
  }
  #pragma unroll
  for (int i = 0; i < 4; i++)
    #pragma unroll
    for (int j = 0; j < 4; j++)
      #pragma unroll
      for (int ri = 0; ri < 4; ri++)
        pbuf[wave][(16 * i + kq * 4 + ri) * 64 + 16 * j + fr] =
            (short)__bfloat16_as_ushort(f2b(acc[i][j][ri]));
  __syncthreads();
  {
    int e0 = threadIdx.x * 16;
    float* Mp = Mpart + (((size_t)c * HH + h) << 12) + e0;
    #pragma unroll
    for (int e = 0; e < 16; e++) {
      Mp[e] = b2f(pbuf[0][e0 + e]) + b2f(pbuf[1][e0 + e]) +
              b2f(pbuf[2][e0 + e]) + b2f(pbuf[3][e0 + e]);
    }
  }
}

// ---------------------------------------------------------------------------
// Attention phase 2: Ms = 0.125 * sum_{c<8} Mpart[c][h]; then
// Gt[n][h*64+d1] = (Ms @ Wo_h)[d1][n] for a 128-n tile. grid (6, 12).
// ---------------------------------------------------------------------------
__global__ __launch_bounds__(256) void attn_wo_kernel(
    const float* __restrict__ Mpart, const bf16* __restrict__ Wo_t,
    bf16* __restrict__ Gt) {
  __shared__ short Ms[4096];
  const int nt = blockIdx.x, h = blockIdx.y;
  const int lane = threadIdx.x & 63, wave = threadIdx.x >> 6;
  const int fr = lane & 15, kq = lane >> 4;

  {
    int e0 = threadIdx.x * 16;
    float s[16];
    #pragma unroll
    for (int e = 0; e < 16; e++) s[e] = 0.f;
    #pragma unroll
    for (int c = 0; c < 8; c++) {
      const float* P = Mpart + (((size_t)c * HH + h) << 12) + e0;
      #pragma unroll
      for (int e = 0; e < 16; e += 4) {
        float4 q = *(const float4*)(P + e);
        s[e] += q.x; s[e + 1] += q.y; s[e + 2] += q.z; s[e + 3] += q.w;
      }
    }
    #pragma unroll
    for (int e = 0; e < 16; e++)
      Ms[e0 + e] = (short)__bfloat16_as_ushort(f2b(s[e] * 0.125f));
  }
  __syncthreads();

  const int nb = nt * 128 + wave * 32;
  f32x4 g[4][2] = {};
  #pragma unroll
  for (int s = 0; s < 2; s++) {
    short8 a[4], b[2];
    #pragma unroll
    for (int i = 0; i < 4; i++)
      a[i] = *(const short8*)(Ms + (16 * i + fr) * 64 + s * 32 + kq * 8);
    #pragma unroll
    for (int j = 0; j < 2; j++)
      b[j] = *(const short8*)((const short*)Wo_t +
             (size_t)(nb + 16 * j + fr) * 768 + h * 64 + s * 32 + kq * 8);
    #pragma unroll
    for (int i = 0; i < 4; i++)
      #pragma unroll
      for (int j = 0; j < 2; j++)
        g[i][j] = __builtin_amdgcn_mfma_f32_16x16x32_bf16(a[i], b[j], g[i][j], 0, 0, 0);
  }
  #pragma unroll
  for (int i = 0; i < 4; i++)
    #pragma unroll
    for (int j = 0; j < 2; j++) {
      const int c = nb + 16 * j + fr;
      const int d1 = 16 * i + kq * 4;
      __align__(8) bf16 tb[4];
      #pragma unroll
      for (int ri = 0; ri < 4; ri++) tb[ri] = f2b(g[i][j][ri]);
      *(short4*)((short*)Gt + (size_t)c * 768 + h * 64 + d1) = *(short4*)&tb[0];
    }
}

// ---------------------------------------------------------------------------
extern "C" void kernel_launch(void* const* d_in, const int* in_sizes, int n_in,
                              void* d_out, int out_size, void* d_ws, size_t ws_size,
                              hipStream_t stream) {
  const float* emb  = (const float*)d_in[0];
  const float* wpe  = (const float*)d_in[1];
  const float* ln1g = (const float*)d_in[2];
  const float* ln1b = (const float*)d_in[3];
  const float* Wq   = (const float*)d_in[4];
  const float* bq   = (const float*)d_in[5];
  const float* Wk   = (const float*)d_in[6];
  const float* bk   = (const float*)d_in[7];
  const float* Wv   = (const float*)d_in[8];
  const float* bv   = (const float*)d_in[9];
  const float* Wo   = (const float*)d_in[10];
  const float* bo   = (const float*)d_in[11];
  const float* ln2g = (const float*)d_in[12];
  const float* ln2b = (const float*)d_in[13];
  const float* W1   = (const float*)d_in[14];
  const float* b1   = (const float*)d_in[15];
  const float* W2   = (const float*)d_in[16];
  const float* b2   = (const float*)d_in[17];
  const float* lnfg = (const float*)d_in[18];
  const float* lnfb = (const float*)d_in[19];

  // Workspace (~106 MB of 256 MiB)
  char* w = (char*)d_ws;
  bf16*  WtAll = (bf16*)w;   w += (size_t)4 * 7077888 * 2;    // 56.6 MB
  float* bqkvA = (float*)w;  w += (size_t)4 * 2304 * 4;
  float* x     = (float*)w;  w += (size_t)SS * EE * 4;        // 6.3 MB
  bf16*  hb    = (bf16*)w;   w += (size_t)SS * EE * 2;        // 3.1 MB
  bf16*  qkvQ  = (bf16*)w;   w += (size_t)SS * EE * 2;        // 3.1 MB
  bf16*  kvT   = (bf16*)w;   w += (size_t)1536 * 2048 * 2;    // 6.3 MB
  bf16*  Gt    = (bf16*)w;   w += (size_t)EE * EE * 2;        // 1.2 MB
  bf16*  mb2   = (bf16*)w;   w += (size_t)SS * FFF * 2;       // 12.6 MB
  float* cpart = (float*)w;  w += (size_t)2 * SS * EE * 4;    // 12.6 MB
  float* Mpart = (float*)w;  w += (size_t)8 * HH * 64 * 64 * 4;  // 1.6 MB

  dim3 blk(256);
  transpose_all_kernel<<<13825, blk, 0, stream>>>(
      Wq, Wk, Wv, Wo, W1, W2, WtAll, bq, bk, bv, bqkvA);

  for (int l = 0; l < LL; l++) {
    bf16* Wl = WtAll + (size_t)l * 7077888;
    bf16* Wqkv_t = Wl;
    bf16* Wo_t   = Wl + 1769472;
    bf16* W1_t   = Wl + 2359296;
    bf16* W2_t   = Wl + 4718592;

    if (l == 0) {
      // x = emb + wpe, LN -> hb
      ln_fused_kernel<bf16><<<SS, blk, 0, stream>>>(
          x, nullptr, emb, 1, wpe, ln1g, ln1b, 1, 0, hb);
    } else {
      // x += b2(prev) + FF2 partials (2), LN -> hb
      ln_fused_kernel<bf16><<<SS, blk, 0, stream>>>(
          x, b2 + (l - 1) * EE, cpart, 2, nullptr,
          ln1g + l * EE, ln1b + l * EE, 1, 1, hb);
    }
    // fused QKV GEMM (64x96 tile, 768 blocks = 3.0/CU)
    gemm_mn_kernel<3><<<dim3(24, 32), blk, 0, stream>>>(
        hb, EE, Wqkv_t, bqkvA + l * 2304, qkvQ, kvT, nullptr, EE, 2304, 4, 0);
    // attention: partial K^T V (96 blocks), then reduce x Wo (72 blocks)
    attn_kv_kernel<<<dim3(HH, 8), blk, 0, stream>>>(kvT, Mpart);
    attn_wo_kernel<<<dim3(6, HH), blk, 0, stream>>>(Mpart, Wo_t, Gt);
    // x += Q @ Gt^T + bo  (384 blocks, direct residual, 64-tile dbuf)
    gemm_resid_kernel<<<dim3(12, 32), blk, 0, stream>>>(
        qkvQ, EE, Gt, bo + l * EE, x, EE);
    ln_fused_kernel<bf16><<<SS, blk, 0, stream>>>(
        x, nullptr, nullptr, 0, nullptr, ln2g + l * EE, ln2b + l * EE, 0, 1, hb);
    // FF1 + GELU  (64x128 tile, 768 blocks = 3.0/CU)
    gemm_mn_kernel<4><<<dim3(24, 32), blk, 0, stream>>>(
        hb, EE, W1_t, b1 + l * FFF, mb2, nullptr, nullptr, EE, FFF, 1, 0);
    // FF2 split-K=2 partials (64x96 tile, 512 blocks = 2.0/CU)
    gemm_mn_kernel<3><<<dim3(8, 32, 2), blk, 0, stream>>>(
        mb2, FFF, W2_t, nullptr, nullptr, nullptr, cpart, FFF, EE, 2, 1536);
  }
  ln_fused_kernel<float><<<SS, blk, 0, stream>>>(
      x, b2 + 3 * EE, cpart, 2, nullptr, lnfg, lnfb, 0, 1, (float*)d_out);
}

// Round 11
// 540.540 us; speedup vs baseline: 1.0264x; 1.0264x over previous
//
#include <hip/hip_runtime.h>
#include <hip/hip_bf16.h>
#include <math.h>

#define SS 2048
#define EE 768
#define HH 12
#define DHH 64
#define FFF 3072
#define LL 4

typedef __hip_bfloat16 bf16;
typedef __attribute__((ext_vector_type(8))) short short8;
typedef __attribute__((ext_vector_type(4))) float f32x4;

__device__ __forceinline__ float b2f(short u) {
  union { unsigned int i; float f; } v;
  v.i = ((unsigned int)(unsigned short)u) << 16;
  return v.f;
}
__device__ __forceinline__ bf16 f2b(float f) { return __float2bfloat16(f); }
__device__ __forceinline__ unsigned int f2bu(float f) {
  return (unsigned int)__bfloat16_as_ushort(__float2bfloat16(f));
}

__device__ __forceinline__ void async_ld16(const void* g, void* l) {
  __builtin_amdgcn_global_load_lds(
      (const __attribute__((address_space(1))) void*)g,
      (__attribute__((address_space(3))) void*)l, 16, 0, 0);
}

// Bijective XCD-aware block remap (T1): linear bid -> p so each XCD
// (bid % 8 under round-robin dispatch) owns a CONTIGUOUS run of p.
// Decompose p y-fastest so an XCD's blocks share 1-3 B-panels (x) across
// all m-bands (y) -> B-panel stays resident in that XCD's 4 MB L2.
// Requires nwg % 8 == 0 (all our GEMM grids: 768/768/512/384).
__device__ __forceinline__ void xcd_remap(int& bx, int& by, int& bz) {
  const int gx = gridDim.x, gy = gridDim.y;
  const int bid = blockIdx.x + gx * (blockIdx.y + gy * blockIdx.z);
  const int nwg = gx * gy * gridDim.z;
  const int p = (bid & 7) * (nwg >> 3) + (bid >> 3);
  by = p % gy;
  bx = (p / gy) % gx;
  bz = p / (gy * gx);
}

// ---------------------------------------------------------------------------
// Fused LN: v = (readx ? x : 0) + bias + sum(parts) + extra; optional x
// writeback; out = LN(v).
// ---------------------------------------------------------------------------
template <typename OutT>
__global__ __launch_bounds__(256) void ln_fused_kernel(
    float* x, const float* __restrict__ bias, const float* __restrict__ part,
    int nparts, const float* __restrict__ extra,
    const float* __restrict__ g, const float* __restrict__ bta,
    int writeback, int readx, OutT* __restrict__ out) {
  int row = blockIdx.x;
  int tid = threadIdx.x;
  float* xr = x + (size_t)row * EE;
  float v0 = 0.f, v1 = 0.f, v2 = 0.f;
  if (readx) { v0 = xr[tid]; v1 = xr[tid + 256]; v2 = xr[tid + 512]; }
  if (bias) { v0 += bias[tid]; v1 += bias[tid + 256]; v2 += bias[tid + 512]; }
  for (int p = 0; p < nparts; p++) {
    const float* pr = part + (size_t)p * SS * EE + (size_t)row * EE;
    v0 += pr[tid]; v1 += pr[tid + 256]; v2 += pr[tid + 512];
  }
  if (extra) {
    const float* er = extra + (size_t)row * EE;
    v0 += er[tid]; v1 += er[tid + 256]; v2 += er[tid + 512];
  }
  if (writeback) { xr[tid] = v0; xr[tid + 256] = v1; xr[tid + 512] = v2; }
  float s  = v0 + v1 + v2;
  float s2 = v0 * v0 + v1 * v1 + v2 * v2;
  #pragma unroll
  for (int off = 32; off >= 1; off >>= 1) {
    s  += __shfl_down(s,  off);
    s2 += __shfl_down(s2, off);
  }
  __shared__ float red[8];
  __shared__ float mb[2];
  int lane = tid & 63, wid = tid >> 6;
  if (lane == 0) { red[wid] = s; red[4 + wid] = s2; }
  __syncthreads();
  if (tid == 0) {
    float ts  = red[0] + red[1] + red[2] + red[3];
    float ts2 = red[4] + red[5] + red[6] + red[7];
    float mu  = ts * (1.0f / EE);
    float var = ts2 * (1.0f / EE) - mu * mu;
    mb[0] = mu; mb[1] = rsqrtf(var + 1e-5f);
  }
  __syncthreads();
  float mu = mb[0], rs = mb[1];
  OutT* orow = out + (size_t)row * EE;
  float o0 = (v0 - mu) * rs * g[tid]       + bta[tid];
  float o1 = (v1 - mu) * rs * g[tid + 256] + bta[tid + 256];
  float o2 = (v2 - mu) * rs * g[tid + 512] + bta[tid + 512];
  if constexpr (sizeof(OutT) == 4) {
    orow[tid] = o0; orow[tid + 256] = o1; orow[tid + 512] = o2;
  } else {
    orow[tid] = f2b(o0); orow[tid + 256] = f2b(o1); orow[tid + 512] = f2b(o2);
  }
}

// ---------------------------------------------------------------------------
// Mega-transpose: known-good 64k x 32n [32][33] version (0 bank conflicts,
// accepted floor; no inter-block reuse -> no XCD swizzle, per T1 nulls).
// Block 13824 does the qkv bias concat.
// ---------------------------------------------------------------------------
__global__ __launch_bounds__(256) void transpose_all_kernel(
    const float* __restrict__ Wq, const float* __restrict__ Wk,
    const float* __restrict__ Wv, const float* __restrict__ Wo,
    const float* __restrict__ W1, const float* __restrict__ W2,
    bf16* __restrict__ WtAll,
    const float* __restrict__ bq, const float* __restrict__ bk,
    const float* __restrict__ bv, float* __restrict__ bqkvA) {
  int bid = blockIdx.x;
  if (bid == 13824) {  // bias concat: 4 layers x 2304
    #pragma unroll
    for (int i = 0; i < 36; i++) {
      int gidx = i * 256 + threadIdx.x;
      int l = gidx / 2304, ii = gidx % 2304;
      bqkvA[gidx] = (ii < 768) ? bq[l * 768 + ii]
                  : (ii < 1536 ? bk[l * 768 + ii - 768] : bv[l * 768 + ii - 1536]);
    }
    return;
  }
  __shared__ unsigned int lds[32][33];
  int l = bid / 3456, r = bid % 3456;
  bf16* base = WtAll + (size_t)l * 7077888;
  const float* src; bf16* dst; int K, N, rr;
  if (r < 864) {
    int m = r / 288; rr = r % 288;
    src = (m == 0 ? Wq : m == 1 ? Wk : Wv) + (size_t)l * EE * EE;
    dst = base + (size_t)m * 589824; K = 768; N = 768;
  } else if (r < 1152) {
    rr = r - 864; src = Wo + (size_t)l * EE * EE; dst = base + 1769472; K = 768; N = 768;
  } else if (r < 2304) {
    rr = r - 1152; src = W1 + (size_t)l * EE * FFF; dst = base + 2359296; K = 768; N = 3072;
  } else {
    rr = r - 2304; src = W2 + (size_t)l * FFF * EE; dst = base + 4718592; K = 3072; N = 768;
  }
  int ntn = N >> 5;
  int k0 = (rr / ntn) * 64, n0 = (rr % ntn) * 32;
  int kp = threadIdx.x >> 3, ns = (threadIdx.x & 7) * 4;
  const float* s0 = src + (size_t)(k0 + 2 * kp) * N + n0 + ns;
  float4 e = *(const float4*)s0;
  float4 o = *(const float4*)(s0 + N);
  lds[ns + 0][kp] = (f2bu(o.x) << 16) | f2bu(e.x);
  lds[ns + 1][kp] = (f2bu(o.y) << 16) | f2bu(e.y);
  lds[ns + 2][kp] = (f2bu(o.z) << 16) | f2bu(e.z);
  lds[ns + 3][kp] = (f2bu(o.w) << 16) | f2bu(e.w);
  __syncthreads();
  int n = threadIdx.x >> 3, kp4 = (threadIdx.x & 7) * 4;
  uint4 ov;
  ov.x = lds[n][kp4];     ov.y = lds[n][kp4 + 1];
  ov.z = lds[n][kp4 + 2]; ov.w = lds[n][kp4 + 3];
  unsigned int* d = (unsigned int*)dst + (size_t)(n0 + n) * (K >> 1) + (k0 >> 1) + kp4;
  *(uint4*)d = ov;
}

// ---------------------------------------------------------------------------
// bf16 MFMA GEMM, 64 x (NF*32) tile, 2-phase double-buffered, __syncthreads
// drain (known-good loop), + XCD-aware block remap (T1) so the 32 blocks
// sharing each B-panel land on ONE XCD's L2 (B re-read = 150 MB/dispatch
// for FF1 otherwise). NF=4: 64x128 (FF1 grid 768 = 3.0/CU). NF=3: 64x96
// (QKV 768 = 3.0/CU; FF2 512 = 2.0/CU). 4 waves (2x2), BK=64, XOR swizzle.
// Modes: 1: GELU->bf16 (ld N)
//        4: QKV: n<768 -> Cv bf16 ld 768; n>=768 -> transposed short4 into
//           Cv2 = kvT[(n-768)][2048]
//        2: split-K fp32 partial: part[z*S*E + idx] = acc (no bias)
// ---------------------------------------------------------------------------
template <int NF>
__global__ __launch_bounds__(256) void gemm_mn_kernel(
    const bf16* __restrict__ A, int lda, const bf16* __restrict__ Bt,
    const float* __restrict__ bias, void* __restrict__ Cv, void* __restrict__ Cv2,
    float* __restrict__ part, int K, int N, int mode, int Ksplit) {
  __shared__ __align__(16) short As[2][64 * 64];        // 2 x 8 KB
  __shared__ __align__(16) short Bs[2][NF * 32 * 64];   // 2 x NF*4 KB
  const int t = threadIdx.x;
  const int wave = t >> 6, lane = t & 63;

  int bx, by, bz;
  xcd_remap(bx, by, bz);
  const int m0 = by * 64, n0 = bx * (NF * 32);

  const int srow = t >> 3;                  // 0..31
  const int sw   = (t & 7) ^ (srow & 7);    // XOR-swizzled 8-elem chunk
  const bf16* Ag = A  + (size_t)(m0 + srow) * lda + sw * 8;
  const bf16* Bg = Bt + (size_t)(n0 + srow) * K + sw * 8;

  const int fr = lane & 15, kq = lane >> 4;
  const int wm = (wave >> 1) * 32, wn = (wave & 1) * (NF * 16);
  f32x4 acc[2][NF] = {};

  int kBeg = 0, kEnd = K;
  if (mode == 2) { kBeg = bz * Ksplit; kEnd = kBeg + Ksplit; }
  const int nIt = (kEnd - kBeg) >> 6;

  {
    const int k0 = kBeg;
    #pragma unroll
    for (int q = 0; q < 2; q++)
      async_ld16(Ag + (size_t)(q * 32) * lda + k0, As[0] + q * 2048 + wave * 512);
    #pragma unroll
    for (int q = 0; q < NF; q++)
      async_ld16(Bg + (size_t)(q * 32) * K + k0, Bs[0] + q * 2048 + wave * 512);
  }
  __syncthreads();

  for (int it = 0; it < nIt; ++it) {
    const int cur = it & 1;
    if (it + 1 < nIt) {
      const int k0 = kBeg + (it + 1) * 64;
      short* Ad = As[cur ^ 1];
      short* Bd = Bs[cur ^ 1];
      #pragma unroll
      for (int q = 0; q < 2; q++)
        async_ld16(Ag + (size_t)(q * 32) * lda + k0, Ad + q * 2048 + wave * 512);
      #pragma unroll
      for (int q = 0; q < NF; q++)
        async_ld16(Bg + (size_t)(q * 32) * K + k0, Bd + q * 2048 + wave * 512);
    }
    const short* Ac = As[cur];
    const short* Bc = Bs[cur];
    #pragma unroll
    for (int s = 0; s < 2; s++) {
      short8 a[2], b[NF];
      #pragma unroll
      for (int i = 0; i < 2; i++) {
        int r = wm + 16 * i + fr;
        int p = (kq + 4 * s) ^ (r & 7);
        a[i] = *(const short8*)(Ac + r * 64 + p * 8);
      }
      #pragma unroll
      for (int j = 0; j < NF; j++) {
        int r = wn + 16 * j + fr;
        int p = (kq + 4 * s) ^ (r & 7);
        b[j] = *(const short8*)(Bc + r * 64 + p * 8);
      }
      #pragma unroll
      for (int i = 0; i < 2; i++)
        #pragma unroll
        for (int j = 0; j < NF; j++)
          acc[i][j] = __builtin_amdgcn_mfma_f32_16x16x32_bf16(a[i], b[j], acc[i][j], 0, 0, 0);
    }
    __syncthreads();
  }

  // C/D layout: col = lane&15, row = (lane>>4)*4 + reg
  #pragma unroll
  for (int i = 0; i < 2; i++) {
    #pragma unroll
    for (int j = 0; j < NF; j++) {
      const int r0 = m0 + wm + 16 * i + kq * 4;
      const int c  = n0 + wn + 16 * j + fr;
      if (mode == 2) {
        #pragma unroll
        for (int ri = 0; ri < 4; ri++)
          part[(size_t)bz * SS * EE + (size_t)(r0 + ri) * EE + c] =
              acc[i][j][ri];
      } else if (mode == 4) {
        const float bv = bias[c];
        if (n0 < 768) {
          #pragma unroll
          for (int ri = 0; ri < 4; ri++)
            ((bf16*)Cv)[(size_t)(r0 + ri) * 768 + c] = f2b(acc[i][j][ri] + bv);
        } else {
          __align__(8) bf16 tb[4];
          #pragma unroll
          for (int ri = 0; ri < 4; ri++) tb[ri] = f2b(acc[i][j][ri] + bv);
          *(short4*)((short*)Cv2 + ((size_t)(c - 768) << 11) + r0) = *(short4*)&tb[0];
        }
      } else {
        const float bv = bias[c];
        #pragma unroll
        for (int ri = 0; ri < 4; ri++) {
          float val = acc[i][j][ri] + bv;
          val = 0.5f * val * (1.0f + erff(val * 0.70710678118654752f));
          ((bf16*)Cv)[(size_t)(r0 + ri) * N + c] = f2b(val);
        }
      }
    }
  }
}

// ---------------------------------------------------------------------------
// Residual GEMM (fp32 out), 64x64 tile, N = 768, 2-phase double-buffered
// (known-good) + XCD remap. x[idx] = acc + bias + x[idx]. grid (12, 32).
// ---------------------------------------------------------------------------
__global__ __launch_bounds__(256) void gemm_resid_kernel(
    const bf16* __restrict__ A, int lda, const bf16* __restrict__ Bt,
    const float* __restrict__ bias, float* __restrict__ x, int K) {
  __shared__ __align__(16) short As[2][64 * 64];
  __shared__ __align__(16) short Bs[2][64 * 64];
  const int t = threadIdx.x;
  const int wave = t >> 6, lane = t & 63;

  int bx, by, bz;
  xcd_remap(bx, by, bz);
  const int m0 = by * 64, n0 = bx * 64;

  const int srow = t >> 3;
  const int sw   = (t & 7) ^ (srow & 7);
  const bf16* Ag = A  + (size_t)(m0 + srow) * lda + sw * 8;
  const bf16* Bg = Bt + (size_t)(n0 + srow) * K + sw * 8;

  const int fr = lane & 15, kq = lane >> 4;
  const int wm = (wave >> 1) * 32, wn = (wave & 1) * 32;
  f32x4 acc[2][2] = {};
  const int nIt = K >> 6;

  {
    async_ld16(Ag,                    As[0] + wave * 512);
    async_ld16(Ag + (size_t)32 * lda, As[0] + 2048 + wave * 512);
    async_ld16(Bg,                    Bs[0] + wave * 512);
    async_ld16(Bg + (size_t)32 * K,   Bs[0] + 2048 + wave * 512);
  }
  __syncthreads();

  for (int it = 0; it < nIt; ++it) {
    const int cur = it & 1;
    if (it + 1 < nIt) {
      const int k0 = (it + 1) * 64;
      short* Ad = As[cur ^ 1];
      short* Bd = Bs[cur ^ 1];
      async_ld16(Ag + k0,                    Ad + wave * 512);
      async_ld16(Ag + (size_t)32 * lda + k0, Ad + 2048 + wave * 512);
      async_ld16(Bg + k0,                    Bd + wave * 512);
      async_ld16(Bg + (size_t)32 * K + k0,   Bd + 2048 + wave * 512);
    }
    const short* Ac = As[cur];
    const short* Bc = Bs[cur];
    #pragma unroll
    for (int s = 0; s < 2; s++) {
      short8 a[2], b[2];
      #pragma unroll
      for (int i = 0; i < 2; i++) {
        int r = wm + 16 * i + fr;
        int p = (kq + 4 * s) ^ (r & 7);
        a[i] = *(const short8*)(Ac + r * 64 + p * 8);
      }
      #pragma unroll
      for (int j = 0; j < 2; j++) {
        int r = wn + 16 * j + fr;
        int p = (kq + 4 * s) ^ (r & 7);
        b[j] = *(const short8*)(Bc + r * 64 + p * 8);
      }
      #pragma unroll
      for (int i = 0; i < 2; i++)
        #pragma unroll
        for (int j = 0; j < 2; j++)
          acc[i][j] = __builtin_amdgcn_mfma_f32_16x16x32_bf16(a[i], b[j], acc[i][j], 0, 0, 0);
    }
    __syncthreads();
  }

  #pragma unroll
  for (int i = 0; i < 2; i++) {
    #pragma unroll
    for (int j = 0; j < 2; j++) {
      const int r0 = m0 + wm + 16 * i + kq * 4;
      const int c  = n0 + wn + 16 * j + fr;
      const float bv = bias[c];
      #pragma unroll
      for (int ri = 0; ri < 4; ri++) {
        const size_t idx = (size_t)(r0 + ri) * EE + c;
        x[idx] = acc[i][j][ri] + bv + x[idx];
      }
    }
  }
}

// ---------------------------------------------------------------------------
// Attention phase 1 (dedup): partial M_h = K_h^T V_h over an s-chunk of 256.
// grid (12 heads, 8 chunks) = 96 blocks. Writes fp32 partials.
// ---------------------------------------------------------------------------
__global__ __launch_bounds__(256) void attn_kv_kernel(
    const bf16* __restrict__ kvT, float* __restrict__ Mpart) {
  __shared__ short pbuf[4][4096];
  const int h = blockIdx.x, c = blockIdx.y;
  const int lane = threadIdx.x & 63, wave = threadIdx.x >> 6;
  const int fr = lane & 15, kq = lane >> 4;
  const short* kT = (const short*)kvT + (size_t)h * 64 * 2048;
  const short* vT = (const short*)kvT + (size_t)(768 + h * 64) * 2048;

  f32x4 acc[4][4] = {};
  {
    const int s0 = c * 256 + wave * 64;
    #pragma unroll
    for (int s = 0; s < 2; s++) {
      short8 a[4], b[4];
      #pragma unroll
      for (int i = 0; i < 4; i++)
        a[i] = *(const short8*)(kT + (size_t)(16 * i + fr) * 2048 + s0 + s * 32 + kq * 8);
      #pragma unroll
      for (int j = 0; j < 4; j++)
        b[j] = *(const short8*)(vT + (size_t)(16 * j + fr) * 2048 + s0 + s * 32 + kq * 8);
      #pragma unroll
      for (int i = 0; i < 4; i++)
        #pragma unroll
        for (int j = 0; j < 4; j++)
          acc[i][j] = __builtin_amdgcn_mfma_f32_16x16x32_bf16(a[i], b[j], acc[i][j], 0, 0, 0);
    }
  }
  #pragma unroll
  for (int i = 0; i < 4; i++)
    #pragma unroll
    for (int j = 0; j < 4; j++)
      #pragma unroll
      for (int ri = 0; ri < 4; ri++)
        pbuf[wave][(16 * i + kq * 4 + ri) * 64 + 16 * j + fr] =
            (short)__bfloat16_as_ushort(f2b(acc[i][j][ri]));
  __syncthreads();
  {
    int e0 = threadIdx.x * 16;
    float* Mp = Mpart + (((size_t)c * HH + h) << 12) + e0;
    #pragma unroll
    for (int e = 0; e < 16; e++) {
      Mp[e] = b2f(pbuf[0][e0 + e]) + b2f(pbuf[1][e0 + e]) +
              b2f(pbuf[2][e0 + e]) + b2f(pbuf[3][e0 + e]);
    }
  }
}

// ---------------------------------------------------------------------------
// Attention phase 2: Ms = 0.125 * sum_{c<8} Mpart[c][h]; then
// Gt[n][h*64+d1] = (Ms @ Wo_h)[d1][n] for a 128-n tile. grid (6, 12).
// ---------------------------------------------------------------------------
__global__ __launch_bounds__(256) void attn_wo_kernel(
    const float* __restrict__ Mpart, const bf16* __restrict__ Wo_t,
    bf16* __restrict__ Gt) {
  __shared__ short Ms[4096];
  const int nt = blockIdx.x, h = blockIdx.y;
  const int lane = threadIdx.x & 63, wave = threadIdx.x >> 6;
  const int fr = lane & 15, kq = lane >> 4;

  {
    int e0 = threadIdx.x * 16;
    float s[16];
    #pragma unroll
    for (int e = 0; e < 16; e++) s[e] = 0.f;
    #pragma unroll
    for (int c = 0; c < 8; c++) {
      const float* P = Mpart + (((size_t)c * HH + h) << 12) + e0;
      #pragma unroll
      for (int e = 0; e < 16; e += 4) {
        float4 q = *(const float4*)(P + e);
        s[e] += q.x; s[e + 1] += q.y; s[e + 2] += q.z; s[e + 3] += q.w;
      }
    }
    #pragma unroll
    for (int e = 0; e < 16; e++)
      Ms[e0 + e] = (short)__bfloat16_as_ushort(f2b(s[e] * 0.125f));
  }
  __syncthreads();

  const int nb = nt * 128 + wave * 32;
  f32x4 g[4][2] = {};
  #pragma unroll
  for (int s = 0; s < 2; s++) {
    short8 a[4], b[2];
    #pragma unroll
    for (int i = 0; i < 4; i++)
      a[i] = *(const short8*)(Ms + (16 * i + fr) * 64 + s * 32 + kq * 8);
    #pragma unroll
    for (int j = 0; j < 2; j++)
      b[j] = *(const short8*)((const short*)Wo_t +
             (size_t)(nb + 16 * j + fr) * 768 + h * 64 + s * 32 + kq * 8);
    #pragma unroll
    for (int i = 0; i < 4; i++)
      #pragma unroll
      for (int j = 0; j < 2; j++)
        g[i][j] = __builtin_amdgcn_mfma_f32_16x16x32_bf16(a[i], b[j], g[i][j], 0, 0, 0);
  }
  #pragma unroll
  for (int i = 0; i < 4; i++)
    #pragma unroll
    for (int j = 0; j < 2; j++) {
      const int c = nb + 16 * j + fr;
      const int d1 = 16 * i + kq * 4;
      __align__(8) bf16 tb[4];
      #pragma unroll
      for (int ri = 0; ri < 4; ri++) tb[ri] = f2b(g[i][j][ri]);
      *(short4*)((short*)Gt + (size_t)c * 768 + h * 64 + d1) = *(short4*)&tb[0];
    }
}

// ---------------------------------------------------------------------------
extern "C" void kernel_launch(void* const* d_in, const int* in_sizes, int n_in,
                              void* d_out, int out_size, void* d_ws, size_t ws_size,
                              hipStream_t stream) {
  const float* emb  = (const float*)d_in[0];
  const float* wpe  = (const float*)d_in[1];
  const float* ln1g = (const float*)d_in[2];
  const float* ln1b = (const float*)d_in[3];
  const float* Wq   = (const float*)d_in[4];
  const float* bq   = (const float*)d_in[5];
  const float* Wk   = (const float*)d_in[6];
  const float* bk   = (const float*)d_in[7];
  const float* Wv   = (const float*)d_in[8];
  const float* bv   = (const float*)d_in[9];
  const float* Wo   = (const float*)d_in[10];
  const float* bo   = (const float*)d_in[11];
  const float* ln2g = (const float*)d_in[12];
  const float* ln2b = (const float*)d_in[13];
  const float* W1   = (const float*)d_in[14];
  const float* b1   = (const float*)d_in[15];
  const float* W2   = (const float*)d_in[16];
  const float* b2   = (const float*)d_in[17];
  const float* lnfg = (const float*)d_in[18];
  const float* lnfb = (const float*)d_in[19];

  // Workspace (~106 MB of 256 MiB)
  char* w = (char*)d_ws;
  bf16*  WtAll = (bf16*)w;   w += (size_t)4 * 7077888 * 2;    // 56.6 MB
  float* bqkvA = (float*)w;  w += (size_t)4 * 2304 * 4;
  float* x     = (float*)w;  w += (size_t)SS * EE * 4;        // 6.3 MB
  bf16*  hb    = (bf16*)w;   w += (size_t)SS * EE * 2;        // 3.1 MB
  bf16*  qkvQ  = (bf16*)w;   w += (size_t)SS * EE * 2;        // 3.1 MB
  bf16*  kvT   = (bf16*)w;   w += (size_t)1536 * 2048 * 2;    // 6.3 MB
  bf16*  Gt    = (bf16*)w;   w += (size_t)EE * EE * 2;        // 1.2 MB
  bf16*  mb2   = (bf16*)w;   w += (size_t)SS * FFF * 2;       // 12.6 MB
  float* cpart = (float*)w;  w += (size_t)2 * SS * EE * 4;    // 12.6 MB
  float* Mpart = (float*)w;  w += (size_t)8 * HH * 64 * 64 * 4;  // 1.6 MB

  dim3 blk(256);
  transpose_all_kernel<<<13825, blk, 0, stream>>>(
      Wq, Wk, Wv, Wo, W1, W2, WtAll, bq, bk, bv, bqkvA);

  for (int l = 0; l < LL; l++) {
    bf16* Wl = WtAll + (size_t)l * 7077888;
    bf16* Wqkv_t = Wl;
    bf16* Wo_t   = Wl + 1769472;
    bf16* W1_t   = Wl + 2359296;
    bf16* W2_t   = Wl + 4718592;

    if (l == 0) {
      // x = emb + wpe, LN -> hb
      ln_fused_kernel<bf16><<<SS, blk, 0, stream>>>(
          x, nullptr, emb, 1, wpe, ln1g, ln1b, 1, 0, hb);
    } else {
      // x += b2(prev) + FF2 partials (2), LN -> hb
      ln_fused_kernel<bf16><<<SS, blk, 0, stream>>>(
          x, b2 + (l - 1) * EE, cpart, 2, nullptr,
          ln1g + l * EE, ln1b + l * EE, 1, 1, hb);
    }
    // fused QKV GEMM (64x96 tile, 768 blocks = 3.0/CU, XCD-remap)
    gemm_mn_kernel<3><<<dim3(24, 32), blk, 0, stream>>>(
        hb, EE, Wqkv_t, bqkvA + l * 2304, qkvQ, kvT, nullptr, EE, 2304, 4, 0);
    // attention: partial K^T V (96 blocks), then reduce x Wo (72 blocks)
    attn_kv_kernel<<<dim3(HH, 8), blk, 0, stream>>>(kvT, Mpart);
    attn_wo_kernel<<<dim3(6, HH), blk, 0, stream>>>(Mpart, Wo_t, Gt);
    // x += Q @ Gt^T + bo  (384 blocks, direct residual, XCD-remap)
    gemm_resid_kernel<<<dim3(12, 32), blk, 0, stream>>>(
        qkvQ, EE, Gt, bo + l * EE, x, EE);
    ln_fused_kernel<bf16><<<SS, blk, 0, stream>>>(
        x, nullptr, nullptr, 0, nullptr, ln2g + l * EE, ln2b + l * EE, 0, 1, hb);
    // FF1 + GELU  (64x128 tile, 768 blocks = 3.0/CU, XCD-remap)
    gemm_mn_kernel<4><<<dim3(24, 32), blk, 0, stream>>>(
        hb, EE, W1_t, b1 + l * FFF, mb2, nullptr, nullptr, EE, FFF, 1, 0);
    // FF2 split-K=2 partials (64x96 tile, 512 blocks = 2.0/CU, XCD-remap)
    gemm_mn_kernel<3><<<dim3(8, 32, 2), blk, 0, stream>>>(
        mb2, FFF, W2_t, nullptr, nullptr, nullptr, cpart, FFF, EE, 2, 1536);
  }
  ln_fused_kernel<float><<<SS, blk, 0, stream>>>(
      x, b2 + 3 * EE, cpart, 2, nullptr, lnfg, lnfb, 0, 1, (float*)d_out);
}